// Round 2
// baseline (7165.887 us; speedup 1.0000x reference)
//
#include <hip/hip_runtime.h>

// Problem constants
#define BB    128   // batch
#define LL    2048  // seq len
#define FF    128   // input features
#define HH    256   // hidden
#define OO    128   // output
#define NTICK 5
#define GC    16    // chains per consumer group
#define NCG   8     // consumer groups (blocks 0..7)
#define CH    4     // timesteps per ring chunk
#define DRING 128   // ring depth (timesteps); 24 MB f16
#define NPS   8     // producer col-slices (96 cols each)
#define NPL   16    // producer chunk-lanes
#define MAXT  (LL + NTICK)
#define MAXCH ((MAXT + CH - 1) / CH)
#define RDY8  0x0101010101010101ULL

typedef __attribute__((ext_vector_type(8))) _Float16 half8;
typedef __attribute__((ext_vector_type(4))) float f32x4;

union U64H4 { unsigned long long u; _Float16 h[4]; };

__device__ __forceinline__ float fast_rcp(float x) { return __builtin_amdgcn_rcpf(x); }

// Relaxed system-scope ops (sc0 sc1): bypass L1/L2, coherent at MALL.
__device__ __forceinline__ unsigned long long sysload_u64(const unsigned long long* p) {
  return __hip_atomic_load(p, __ATOMIC_RELAXED, __HIP_MEMORY_SCOPE_SYSTEM);
}
__device__ __forceinline__ void sysstore_u64(unsigned long long* p, unsigned long long v) {
  __hip_atomic_store(p, v, __ATOMIC_RELAXED, __HIP_MEMORY_SCOPE_SYSTEM);
}
__device__ __forceinline__ int sysload_i32(const int* p) {
  return __hip_atomic_load(p, __ATOMIC_RELAXED, __HIP_MEMORY_SCOPE_SYSTEM);
}
__device__ __forceinline__ void sysstore_i32(int* p, int v) {
  __hip_atomic_store(p, v, __ATOMIC_RELAXED, __HIP_MEMORY_SCOPE_SYSTEM);
}
__device__ __forceinline__ void sysstore_u8(unsigned char* p, unsigned char v) {
  __hip_atomic_store(p, v, __ATOMIC_RELAXED, __HIP_MEMORY_SCOPE_SYSTEM);
}

// Raw barrier with LDS-only drain: ring prefetch loads (vmcnt) stay in flight
// across the barrier; the compiler's dep-tracking waits them before first use
// next iteration. "memory" clobbers pin all memory ops on each side.
__device__ __forceinline__ void sync_lds_only() {
  asm volatile("s_waitcnt lgkmcnt(0)" ::: "memory");
  __builtin_amdgcn_s_barrier();
  asm volatile("" ::: "memory");
}

// Ring layout: [slot][col4=0..191][b=0..127][4 x f16] (u64 granules).
// col4 = col/4 where col in [0,768). One u64 holds cols 4*col4..4*col4+3 of
// pre_x for chain b at timestep slot. Producer lane (s,wv,quad) owns
// col4 = 24s+4wv+quad; consumer lane (wv,quad) needs col4 = 64g+8wv+4tl+quad.
//
// MFMA layout note: fragments loaded as B[k][n] (n=lane&15, k=quad*8+j);
// weight fragment passed in the A slot => D-layout: lane nl reg r =
// pre[chain=nl][tilecol + quad*4 + r].  Consumer tilecol(g,tl) =
// 256g + 32wv + 16tl, so lane (wv,quad,nl) holds the matched ci/ig/og
// triplet for chain nl, dims 32wv+16tl+4quad+r -> gates fully in registers.
extern "C" __global__ __launch_bounds__(512, 1)
void lstm_all(const float* __restrict__ x, const int* __restrict__ lens,
              const float* __restrict__ W, const float* __restrict__ R,
              const float* __restrict__ bvec, const float* __restrict__ btk,
              unsigned long long* ring, unsigned char* readyb,
              int* prog, float* __restrict__ h_final)
{
  const int tid  = threadIdx.x;
  const int lane = tid & 63;
  const int wv   = tid >> 6;
  const int quad = lane >> 4;
  const int nl   = lane & 15;
  const int bx   = blockIdx.x;

  __shared__ int lens_s[BB];
  if (tid < BB) lens_s[tid] = lens[tid];
  __syncthreads();

  if (bx < NCG) {
    // ======================= CONSUMER =======================
    const int cg = bx, cbase = cg * GC;
    __shared__ _Float16 h_s[2][GC][264];   // double-buffered hidden state (f16)

    for (int i = tid; i < 2 * GC * 264; i += 512) ((_Float16*)h_s)[i] = (_Float16)0.f;

    int mxl = 0;
    #pragma unroll
    for (int i = 0; i < GC; i++) mxl = max(mxl, lens_s[cbase + i]);
    const int Tg = mxl + NTICK;

    // R fragments, register-stationary. Wave wv owns 6 col-tiles
    // {256g + 32wv + 16tl}: loaded as B[k][n]: n=lane&15, k=quad*8+j.
    half8 rfr[6][8];
    #pragma unroll
    for (int g = 0; g < 3; g++) {
      #pragma unroll
      for (int tl = 0; tl < 2; tl++) {
        const int col = g * 256 + wv * 32 + tl * 16 + nl;
        #pragma unroll
        for (int kc = 0; kc < 8; kc++) {
          const int k0 = kc * 32 + quad * 8;
          half8 v;
          #pragma unroll
          for (int j = 0; j < 8; j++) v[j] = (_Float16)R[(k0 + j) * (3 * HH) + col];
          rfr[g * 2 + tl][kc] = v;
        }
      }
    }

    const int b    = cbase + nl;      // this lane's chain
    const int lenN = lens_s[b];
    const int cb   = wv * 8 + quad;   // col4 base contribution

    // register-resident cell + hidden state (8 dims/lane)
    float cst[8], hst[8];
    #pragma unroll
    for (int d = 0; d < 8; d++) { cst[d] = 0.f; hst[d] = 0.f; }

    const unsigned long long* rb = (const unsigned long long*)readyb;

    // initial: wait chunk 0, prefetch xw(0)
    while (sysload_u64(rb + 0) != RDY8) {}
    asm volatile("" ::: "memory");
    unsigned long long xw[6];
    #pragma unroll
    for (int g = 0; g < 3; g++)
      #pragma unroll
      for (int tl = 0; tl < 2; tl++)
        xw[g * 2 + tl] = sysload_u64(ring + (g * 64 + tl * 4 + cb) * 128 + b);
    unsigned long long rvn = sysload_u64(rb + 1);
    int cur_chunk = 0;
    __syncthreads();

    for (int t = 0; t < Tg; ++t) {
      // ---- consume previous prefetch (loads had a full iteration in flight)
      U64H4 u[6];
      #pragma unroll
      for (int i = 0; i < 6; i++) u[i].u = xw[i];

      // ---- issue prefetch for t+1; stays in flight across the barrier
      if (t + 1 < Tg) {
        const int nc = (t + 1) >> 2;
        if (nc != cur_chunk) {
          while (rvn != RDY8) rvn = sysload_u64(rb + nc);
          cur_chunk = nc;
          rvn = (nc + 1 < MAXCH) ? sysload_u64(rb + nc + 1) : RDY8;
        }
        asm volatile("" ::: "memory");
        const int slot = (t + 1) & (DRING - 1);
        const unsigned long long* rp = ring + (long)slot * (192 * 128);
        #pragma unroll
        for (int g = 0; g < 3; g++)
          #pragma unroll
          for (int tl = 0; tl < 2; tl++)
            xw[g * 2 + tl] = sysload_u64(rp + (g * 64 + tl * 4 + cb) * 128 + b);
      }

      // ---- recurrent MFMA: pre_h for this wave's 6 column-tiles
      f32x4 acc[6];
      #pragma unroll
      for (int i = 0; i < 6; i++) acc[i] = (f32x4){0.f, 0.f, 0.f, 0.f};
      if (t > 0) {
        const _Float16* hrow = &h_s[t & 1][nl][0];
        #pragma unroll
        for (int kc = 0; kc < 8; kc++) {
          const half8 a = *(const half8*)(hrow + kc * 32 + quad * 8);
          #pragma unroll
          for (int i = 0; i < 6; i++)
            acc[i] = __builtin_amdgcn_mfma_f32_16x16x32_f16(rfr[i][kc], a, acc[i], 0, 0, 0);
        }
      }

      // ---- gate phase, fully in registers (acc idx: g*2+tl)
      if (t < lenN + NTICK) {
        #pragma unroll
        for (int tl = 0; tl < 2; tl++) {
          #pragma unroll
          for (int r = 0; r < 4; r++) {
            const int d = tl * 4 + r;
            const float pc = acc[tl][r]     + (float)u[tl].h[r];
            const float pi = acc[2 + tl][r] + (float)u[2 + tl].h[r];
            const float po = acc[4 + tl][r] + (float)u[4 + tl].h[r];
            // dc = tanh(pc)*sigmoid(pi) = (e^{2pc}-1) / ((e^{2pc}+1)(1+e^{-pi}))
            const float ea = __expf(2.f * __builtin_fminf(pc, 15.f));
            const float eb = __expf(-pi);
            const float cn = cst[d] + (ea - 1.f) * fast_rcp((ea + 1.f) * (1.f + eb));
            const float ec = __expf(2.f * __builtin_fminf(cn, 15.f));
            const float ed = __expf(-po);
            hst[d] = (ec - 1.f) * fast_rcp((ec + 1.f) * (1.f + ed));
            cst[d] = cn;
          }
        }
        if (t == lenN + NTICK - 1) {
          float* hf = h_final + b * HH + wv * 32 + quad * 4;
          float4 v0, v1;
          v0.x = hst[0]; v0.y = hst[1]; v0.z = hst[2]; v0.w = hst[3];
          v1.x = hst[4]; v1.y = hst[5]; v1.z = hst[6]; v1.w = hst[7];
          *(float4*)(hf)      = v0;
          *(float4*)(hf + 16) = v1;
        }
      }

      // ---- publish h(t) into the other buffer (always, incl. frozen lanes)
      {
        U64H4 p0, p1;
        #pragma unroll
        for (int r = 0; r < 4; r++) {
          p0.h[r] = (_Float16)hst[r];
          p1.h[r] = (_Float16)hst[4 + r];
        }
        _Float16* hw = &h_s[(t + 1) & 1][nl][wv * 32 + quad * 4];
        *(unsigned long long*)(hw)      = p0.u;   // dims 32wv+4quad   .. +3
        *(unsigned long long*)(hw + 16) = p1.u;   // dims 32wv+16+4quad.. +3
      }

      sync_lds_only();   // ONE barrier/step; vmcnt (ring prefetch) not drained
      if (tid == 0) sysstore_i32(prog + cg, t);
    }
    if (tid == 0) sysstore_i32(prog + cg, 1 << 20);

  } else {
    // ======================= PRODUCER =======================
    const int pid = bx - NCG;       // 0..127
    const int s   = pid & 7;        // col slice (96 cols)
    const int pl  = pid >> 3;       // chunk lane 0..15

    int mxall = 0;
    #pragma unroll 8
    for (int i = 0; i < BB; i++) mxall = max(mxall, lens_s[i]);
    const int Tall = mxall + NTICK;
    const int nch  = (Tall + CH - 1) / CH;

    half8 wfr[4];
    float bias4[4], tick4[4];
    int c4b = 0;
    if (wv < 6) {
      const int col0w = s * 96 + wv * 16;
      c4b = (s * 24 + wv * 4 + quad) * 128;      // [col4][b] base (u64 units)
      #pragma unroll
      for (int kc = 0; kc < 4; kc++) {
        const int k0 = kc * 32 + quad * 8;
        half8 v;
        #pragma unroll
        for (int j = 0; j < 8; j++) v[j] = (_Float16)W[(k0 + j) * (3 * HH) + col0w + nl];
        wfr[kc] = v;
      }
      *(float4*)bias4 = *(const float4*)(bvec + col0w + quad * 4);
      *(float4*)tick4 = *(const float4*)(btk  + col0w + quad * 4);
    }

    for (int c = pl; c < nch; c += NPL) {
      if (c * CH >= DRING) {           // flow control: don't overwrite unread slots
        if (tid == 0) {
          const int need = c * CH + CH - DRING;
          for (;;) {
            int mn = 0x7fffffff;
            #pragma unroll
            for (int g = 0; g < NCG; g++) mn = min(mn, sysload_i32(prog + g));
            if (mn >= need) break;
          }
        }
        __syncthreads();
      }
      if (wv < 6) {
        for (int tt = 0; tt < CH; tt++) {
          const int t = c * CH + tt;
          const int slot = t & (DRING - 1);
          unsigned long long* sp = ring + (long)slot * (192 * 128) + c4b;
          #pragma unroll 2
          for (int bt = 0; bt < 8; bt++) {
            const int bb = bt * 16 + nl;
            const int lenb = lens_s[bb];
            f32x4 acc = {0.f, 0.f, 0.f, 0.f};
            if (t < LL) {
              const float* xp = x + ((long)bb * LL + t) * FF + quad * 8;
              #pragma unroll
              for (int kc = 0; kc < 4; kc++) {
                const float4 u0 = *(const float4*)(xp + kc * 32);
                const float4 u1 = *(const float4*)(xp + kc * 32 + 4);
                half8 a;
                a[0] = (_Float16)u0.x; a[1] = (_Float16)u0.y;
                a[2] = (_Float16)u0.z; a[3] = (_Float16)u0.w;
                a[4] = (_Float16)u1.x; a[5] = (_Float16)u1.y;
                a[6] = (_Float16)u1.z; a[7] = (_Float16)u1.w;
                // W-frag in A slot, x-frag in B slot:
                // lane nl reg r = pre_x[batch=bt*16+nl][col0w+quad*4+r]
                acc = __builtin_amdgcn_mfma_f32_16x16x32_f16(wfr[kc], a, acc, 0, 0, 0);
              }
            }
            U64H4 pk;
            const bool in_x  = (t < lenb);
            const bool in_tk = (t >= lenb) && (t < lenb + NTICK);
            #pragma unroll
            for (int r = 0; r < 4; r++) {
              float v = bias4[r];
              if (in_x)  v += acc[r];
              if (in_tk) v += tick4[r];
              pk.h[r] = (_Float16)v;
            }
            sysstore_u64(sp + bb, pk.u);
          }
        }
      }
      __syncthreads();   // per-wave s_waitcnt vmcnt(0) before barrier => stores drained
      if (tid == 0) sysstore_u8(readyb + c * 8 + s, (unsigned char)1);
    }
  }
}

// out1 = h @ Wp^T + bp   (128x256)
extern "C" __global__ void proj_hp(const float* __restrict__ h,
                                   const float* __restrict__ Wp,
                                   const float* __restrict__ bp,
                                   float* __restrict__ hp)
{
  const int bb = blockIdx.x;
  const int j  = threadIdx.x;  // 256
  const float4* hv = (const float4*)(h + bb * HH);
  const float4* wr = (const float4*)(Wp + j * HH);
  float s = 0.f;
  for (int k = 0; k < HH / 4; k++) {
    const float4 a = hv[k], w = wr[k];
    s += a.x * w.x + a.y * w.y + a.z * w.z + a.w * w.w;
  }
  hp[bb * HH + j] = s + bp[j];
}

// out = hp @ Wo^T + bo   (128x128)
extern "C" __global__ void proj_out(const float* __restrict__ hp,
                                    const float* __restrict__ Wo,
                                    const float* __restrict__ bo,
                                    float* __restrict__ out)
{
  const int bb = blockIdx.x;
  const int o  = threadIdx.x;  // 128
  const float4* hv = (const float4*)(hp + bb * HH);
  const float4* wr = (const float4*)(Wo + o * HH);
  float s = 0.f;
  for (int k = 0; k < HH / 4; k++) {
    const float4 a = hv[k], w = wr[k];
    s += a.x * w.x + a.y * w.y + a.z * w.z + a.w * w.w;
  }
  out[bb * OO + o] = s + bo[o];
}

extern "C" void kernel_launch(void* const* d_in, const int* in_sizes, int n_in,
                              void* d_out, int out_size, void* d_ws, size_t ws_size,
                              hipStream_t stream)
{
  const float* x    = (const float*)d_in[0];
  const int*   ln   = (const int*)  d_in[1];
  const float* W    = (const float*)d_in[2];
  const float* R    = (const float*)d_in[3];
  const float* bvec = (const float*)d_in[4];
  const float* btk  = (const float*)d_in[5];
  const float* Wp   = (const float*)d_in[6];
  const float* bp   = (const float*)d_in[7];
  const float* Wo   = (const float*)d_in[8];
  const float* bo   = (const float*)d_in[9];
  float* out = (float*)d_out;

  // Workspace layout. No init pass needed:
  //   prog[] poisoned 0xAA..: negative => producers wait until consumers publish.
  //   readyb[] poisoned 0xAA != 1 => consumers wait until producers publish.
  char* ws = (char*)d_ws;
  int*                prog    = (int*)ws;                       // 32 B
  unsigned char*      readyb  = (unsigned char*)(ws + 64);      // MAXCH*8 = 4112 B
  float*              h_final = (float*)(ws + 8192);            // 128 KB
  float*              hp      = (float*)(ws + 8192 + 131072);   // 128 KB
  unsigned long long* ring    = (unsigned long long*)(ws + (1 << 20));  // 24 MB

  hipLaunchKernelGGL(lstm_all, dim3(NCG + NPS * NPL), dim3(512), 0, stream,
                     x, ln, W, R, bvec, btk, ring, readyb, prog, h_final);
  hipLaunchKernelGGL(proj_hp,  dim3(BB), dim3(HH), 0, stream, h_final, Wp, bp, hp);
  hipLaunchKernelGGL(proj_out, dim3(BB), dim3(OO), 0, stream, hp, Wo, bo, out);
}

// Round 5
// 6241.585 us; speedup vs baseline: 1.1481x; 1.1481x over previous
//
#include <hip/hip_runtime.h>

// Problem constants
#define BB    128   // batch
#define LL    2048  // seq len
#define FF    128   // input features
#define HH    256   // hidden
#define OO    128   // output
#define NTICK 5
#define GC    16    // chains per consumer group
#define NCG   8     // consumer groups (blocks 0..7)
#define CH    4     // timesteps per ring chunk
#define DRING 128   // ring depth (timesteps); 25 MB f16
#define NPS   8     // producer col-slices (96 cols each)
#define NPL   16    // producer chunk-lanes
#define MAXT  (LL + NTICK)
#define MAXCH ((MAXT + CH - 1) / CH)
#define RDY8  0x0101010101010101ULL

// Gate-column pre-scales folded into W/R/b/tick so the gate body uses bare
// v_exp_f32 (exp2) with no constant multiplies:
//   ci cols  (0..255):   * 2*log2(e)  -> ea = exp2(pc_s) = e^{2 pc}
//   ig cols (256..511):  * -log2(e)   -> eb = exp2(pi_s) = e^{-pi}
//   og cols (512..767):  * -log2(e)   -> ed = exp2(po_s) = e^{-po}
// Cell state c is kept in ci-scaled units (c' = 2log2e * c).
#define SC_CI  (2.8853900817779268f)
#define SC_GT  (-1.4426950408889634f)

typedef __attribute__((ext_vector_type(8))) _Float16 half8;
typedef __attribute__((ext_vector_type(2))) __fp16 fp16x2;
typedef __attribute__((ext_vector_type(4))) float f32x4;

union U64H8 { unsigned long long u[2]; _Float16 h[8]; fp16x2 p[4]; };
union U64H4 { unsigned long long u; _Float16 h[4]; };

__device__ __forceinline__ float fast_rcp(float x) { return __builtin_amdgcn_rcpf(x); }
__device__ __forceinline__ float fast_exp2(float x) { return __builtin_amdgcn_exp2f(x); }

// Relaxed system-scope ops (sc0 sc1): bypass L1/L2, coherent at MALL.
// RELAXED => no buffer_inv/buffer_wbl2 cache maintenance emitted.
__device__ __forceinline__ unsigned long long sysload_u64(const unsigned long long* p) {
  return __hip_atomic_load(p, __ATOMIC_RELAXED, __HIP_MEMORY_SCOPE_SYSTEM);
}
__device__ __forceinline__ void sysstore_u64(unsigned long long* p, unsigned long long v) {
  __hip_atomic_store(p, v, __ATOMIC_RELAXED, __HIP_MEMORY_SCOPE_SYSTEM);
}
__device__ __forceinline__ int sysload_i32(const int* p) {
  return __hip_atomic_load(p, __ATOMIC_RELAXED, __HIP_MEMORY_SCOPE_SYSTEM);
}
__device__ __forceinline__ void sysstore_i32(int* p, int v) {
  __hip_atomic_store(p, v, __ATOMIC_RELAXED, __HIP_MEMORY_SCOPE_SYSTEM);
}
__device__ __forceinline__ void sysstore_u8(unsigned char* p, unsigned char v) {
  __hip_atomic_store(p, v, __ATOMIC_RELAXED, __HIP_MEMORY_SCOPE_SYSTEM);
}

// Blocks 0..7: consumers (one chain-group of 16 chains per block, 8 waves;
//   R register-stationary, per-step sync = LDS barriers only).
// Blocks 8..135: producers (col-slice s = pid&7, chunk-lane = pid>>3;
//   compute pre_x = bias + tick*[len<=t<len+5] + [t<len]*x_t@W into ring).
//
// MFMA layout note: fragments are loaded as B[k][n] (n=lane&15, k=quad*8+j).
// Passing the WEIGHT fragment in the A slot makes HW read it as A[m=col][k],
// and the activation fragment in the B slot as B[k][n=chain]. Then
// D = W^T·act^T and C-layout reg r of lane nl = pre[chain=nl][col=..+quad*4+r],
// which is what the spill / ring-write code assumes.
extern "C" __global__ __launch_bounds__(512, 1)
void lstm_all(const float* __restrict__ x, const int* __restrict__ lens,
              const float* __restrict__ W, const float* __restrict__ R,
              const float* __restrict__ bvec, const float* __restrict__ btk,
              unsigned long long* ring, unsigned char* readyb,
              int* prog, float* __restrict__ h_final)
{
  const int tid  = threadIdx.x;
  const int lane = tid & 63;
  const int wv   = tid >> 6;
  const int quad = lane >> 4;
  const int nl   = lane & 15;
  const int bx   = blockIdx.x;

  __shared__ int lens_s[BB];
  if (tid < BB) lens_s[tid] = lens[tid];
  __syncthreads();

  if (bx < NCG) {
    // ======================= CONSUMER =======================
    const int cg = bx, cbase = cg * GC;
    __shared__ float    pre_s[GC][772];   // h@R pre-activations, fp32 (scaled units)
    __shared__ float    c_s[GC][260];     // cell state (ci-scaled units)
    __shared__ _Float16 h_s[GC][264];     // hidden state (f16, true units)

    for (int i = tid; i < GC * 772; i += 512) ((float*)pre_s)[i] = 0.f;
    for (int i = tid; i < GC * 260; i += 512) ((float*)c_s)[i] = 0.f;
    for (int i = tid; i < GC * 264; i += 512) ((_Float16*)h_s)[i] = (_Float16)0.f;

    int mxl = 0;
    #pragma unroll
    for (int i = 0; i < GC; i++) mxl = max(mxl, lens_s[cbase + i]);
    const int Tg = mxl + NTICK;

    // R fragments, register-stationary, column-scaled. Wave wv owns cols
    // [wv*96, wv*96+96): loaded as B[k][n]: n = lane&15, k = quad*8+j.
    half8 rfr[6][8];
    const int colw = wv * 96;
    #pragma unroll
    for (int tile = 0; tile < 6; tile++) {
      const int scol = colw + tile * 16;
      const float rsc = (scol < HH) ? SC_CI : SC_GT;
      const int col = scol + nl;
      #pragma unroll
      for (int kc = 0; kc < 8; kc++) {
        const int k0 = kc * 32 + quad * 8;
        half8 v;
        #pragma unroll
        for (int j = 0; j < 8; j++) v[j] = (_Float16)(R[(k0 + j) * (3 * HH) + col] * rsc);
        rfr[tile][kc] = v;
      }
    }

    // gate-thread identity: chain m, h-dims hj..hj+7
    const int m  = tid >> 5;
    const int hj = (tid & 31) * 8;
    const int lenm = lens_s[cbase + m];

    const unsigned long long* rb = (const unsigned long long*)readyb;

    // initial: wait chunk 0, prefetch xw(0)
    while (sysload_u64(rb + 0) != RDY8) {}
    asm volatile("" ::: "memory");
    unsigned long long xw[6];
    {
      const unsigned long long* rp = ring + ((((long)0 * BB + cbase + m) * 768 + hj) >> 2);
      xw[0] = sysload_u64(rp);       xw[1] = sysload_u64(rp + 1);
      xw[2] = sysload_u64(rp + 64);  xw[3] = sysload_u64(rp + 65);
      xw[4] = sysload_u64(rp + 128); xw[5] = sysload_u64(rp + 129);
    }
    unsigned long long rvn = sysload_u64(rb + 1);
    int cur_chunk = 0;
    __syncthreads();

    for (int t = 0; t < Tg; ++t) {
      // ---- recurrent MFMA phase: pre_h = h(t-1) @ R
      if (t > 0) {
        f32x4 acc[6];
        #pragma unroll
        for (int i = 0; i < 6; i++) acc[i] = (f32x4){0.f, 0.f, 0.f, 0.f};
        const _Float16* hrow = &h_s[nl][0];
        #pragma unroll
        for (int kc = 0; kc < 8; kc++) {
          const half8 a = *(const half8*)(hrow + kc * 32 + quad * 8);
          #pragma unroll
          for (int tile = 0; tile < 6; tile++)
            acc[tile] = __builtin_amdgcn_mfma_f32_16x16x32_f16(rfr[tile][kc], a, acc[tile], 0, 0, 0);
        }
        // spill: D = R^T h^T => lane nl reg r = pre[chain=nl][colw+tile*16+quad*4+r]
        #pragma unroll
        for (int tile = 0; tile < 6; tile++)
          *(f32x4*)(&pre_s[nl][colw + tile * 16 + quad * 4]) = acc[tile];
      }
      __syncthreads();

      // ---- gate phase (per-thread; execz-skipped when whole wave frozen)
      if (t < lenm + NTICK) {
        U64H8 uc, ui, uo;
        uc.u[0] = xw[0]; uc.u[1] = xw[1];
        ui.u[0] = xw[2]; ui.u[1] = xw[3];
        uo.u[0] = xw[4]; uo.u[1] = xw[5];
        const float* pr = &pre_s[m][0];
        float pci[8], pig[8], pog[8], cc[8], hh[8];
        *(float4*)(pci)     = *(const float4*)(pr + hj);
        *(float4*)(pci + 4) = *(const float4*)(pr + hj + 4);
        *(float4*)(pig)     = *(const float4*)(pr + 256 + hj);
        *(float4*)(pig + 4) = *(const float4*)(pr + 256 + hj + 4);
        *(float4*)(pog)     = *(const float4*)(pr + 512 + hj);
        *(float4*)(pog + 4) = *(const float4*)(pr + 512 + hj + 4);
        *(float4*)(cc)      = *(const float4*)(&c_s[m][hj]);
        *(float4*)(cc + 4)  = *(const float4*)(&c_s[m][hj + 4]);
        #pragma unroll
        for (int d = 0; d < 8; d++) {
          // scaled units: pc = 2log2e*pc_true, pi = -log2e*pi_true, po = -log2e*po_true
          const float pc = pci[d] + (float)uc.h[d];
          const float pi = pig[d] + (float)ui.h[d];
          const float po = pog[d] + (float)uo.h[d];
          // dc = tanh(pc)*sigmoid(pi) = (e^{2pc}-1) / ((e^{2pc}+1)(1+e^{-pi}))
          const float ea = fast_exp2(__builtin_fminf(pc, 43.0f));   // e^{2 pc_true}
          const float eb = fast_exp2(pi);                           // e^{-pi_true}
          const float t1 = __builtin_fmaf(ea, SC_CI, -SC_CI);       // 2log2e*(ea-1)
          const float cn = __builtin_fmaf(t1, fast_rcp((ea + 1.f) * (1.f + eb)), cc[d]);
          const float ec = fast_exp2(__builtin_fminf(cn, 43.0f));   // e^{2 c_true}
          const float ed = fast_exp2(po);                           // e^{-po_true}
          hh[d] = (ec - 1.f) * fast_rcp((ec + 1.f) * (1.f + ed));
          cc[d] = cn;
        }
        *(float4*)(&c_s[m][hj])     = *(float4*)(cc);
        *(float4*)(&c_s[m][hj + 4]) = *(float4*)(cc + 4);
        U64H8 up;
        up.p[0] = __builtin_amdgcn_cvt_pkrtz(hh[0], hh[1]);
        up.p[1] = __builtin_amdgcn_cvt_pkrtz(hh[2], hh[3]);
        up.p[2] = __builtin_amdgcn_cvt_pkrtz(hh[4], hh[5]);
        up.p[3] = __builtin_amdgcn_cvt_pkrtz(hh[6], hh[7]);
        *(half8*)(&h_s[m][hj]) = *(half8*)up.h;
        if (t == lenm + NTICK - 1) {
          float* hf = h_final + (cbase + m) * HH + hj;
          *(float4*)(hf)     = *(float4*)(hh);
          *(float4*)(hf + 4) = *(float4*)(hh + 4);
        }
      }

      // ---- prefetch xw(t+1) + pipelined chunk-ready gating
      // (skipped once this thread's chain is frozen: whole-wave execz saves
      //  6 uncached MALL loads/thread/step for dead chains)
      if (t + 1 < Tg && t + 1 < lenm + NTICK) {
        const int nc = (t + 1) >> 2;
        if (nc != cur_chunk) {
          while (rvn != RDY8) rvn = sysload_u64(rb + nc);
          cur_chunk = nc;
          rvn = (nc + 1 < MAXCH) ? sysload_u64(rb + nc + 1) : RDY8;
        }
        asm volatile("" ::: "memory");
        const int slot = (t + 1) & (DRING - 1);
        const unsigned long long* rp = ring + ((((long)slot * BB + cbase + m) * 768 + hj) >> 2);
        xw[0] = sysload_u64(rp);       xw[1] = sysload_u64(rp + 1);
        xw[2] = sysload_u64(rp + 64);  xw[3] = sysload_u64(rp + 65);
        xw[4] = sysload_u64(rp + 128); xw[5] = sysload_u64(rp + 129);
      }
      __syncthreads();
      if (tid == 0) sysstore_i32(prog + cg, t);
    }
    if (tid == 0) sysstore_i32(prog + cg, 1 << 20);

  } else {
    // ======================= PRODUCER =======================
    const int pid = bx - NCG;       // 0..127
    const int s   = pid & 7;        // col slice (96 cols)
    const int pl  = pid >> 3;       // chunk lane 0..15

    int mxall = 0;
    #pragma unroll 8
    for (int i = 0; i < BB; i++) mxall = max(mxall, lens_s[i]);
    const int Tall = mxall + NTICK;
    const int nch  = (Tall + CH - 1) / CH;

    half8 wfr[4];
    float bias4[4], tick4[4];
    int col0w = 0;
    if (wv < 6) {
      col0w = s * 96 + wv * 16;
      const float wsc = (col0w < HH) ? SC_CI : SC_GT;   // whole 16-col tile same gate
      #pragma unroll
      for (int kc = 0; kc < 4; kc++) {
        const int k0 = kc * 32 + quad * 8;
        half8 v;
        #pragma unroll
        for (int j = 0; j < 8; j++) v[j] = (_Float16)(W[(k0 + j) * (3 * HH) + col0w + nl] * wsc);
        wfr[kc] = v;
      }
      float4 b4 = *(const float4*)(bvec + col0w + quad * 4);
      float4 t4 = *(const float4*)(btk  + col0w + quad * 4);
      bias4[0] = b4.x * wsc; bias4[1] = b4.y * wsc; bias4[2] = b4.z * wsc; bias4[3] = b4.w * wsc;
      tick4[0] = t4.x * wsc; tick4[1] = t4.y * wsc; tick4[2] = t4.z * wsc; tick4[3] = t4.w * wsc;
    }

    for (int c = pl; c < nch; c += NPL) {
      if (c * CH >= DRING) {           // flow control: don't overwrite unread slots
        if (tid == 0) {
          const int need = c * CH + CH - DRING;
          for (;;) {
            int mn = 0x7fffffff;
            #pragma unroll
            for (int g = 0; g < NCG; g++) mn = min(mn, sysload_i32(prog + g));
            if (mn >= need) break;
          }
        }
        __syncthreads();
      }
      if (wv < 6) {
        for (int tt = 0; tt < CH; tt++) {
          const int t = c * CH + tt;
          const int slot = t & (DRING - 1);
          #pragma unroll 2
          for (int bt = 0; bt < 8; bt++) {
            const int b = bt * 16 + nl;
            const int lenb = lens_s[b];
            f32x4 acc = {0.f, 0.f, 0.f, 0.f};
            if (t < LL) {
              const float* xp = x + ((long)b * LL + t) * FF + quad * 8;
              #pragma unroll
              for (int kc = 0; kc < 4; kc++) {
                const float4 u0 = *(const float4*)(xp + kc * 32);
                const float4 u1 = *(const float4*)(xp + kc * 32 + 4);
                half8 a;
                a[0] = (_Float16)u0.x; a[1] = (_Float16)u0.y;
                a[2] = (_Float16)u0.z; a[3] = (_Float16)u0.w;
                a[4] = (_Float16)u1.x; a[5] = (_Float16)u1.y;
                a[6] = (_Float16)u1.z; a[7] = (_Float16)u1.w;
                // W-frag in A slot, x-frag in B slot: D = W^T x^T =>
                // lane nl reg r = pre_x[batch=bt*16+nl][col0w+quad*4+r]
                acc = __builtin_amdgcn_mfma_f32_16x16x32_f16(wfr[kc], a, acc, 0, 0, 0);
              }
            }
            U64H4 pk;
            const bool in_x  = (t < lenb);
            const bool in_tk = (t >= lenb) && (t < lenb + NTICK);
            #pragma unroll
            for (int r = 0; r < 4; r++) {
              float v = bias4[r];
              if (in_x)  v += acc[r];
              if (in_tk) v += tick4[r];
              pk.h[r] = (_Float16)v;
            }
            sysstore_u64(ring + ((((long)slot * BB + b) * 768 + col0w + quad * 4) >> 2), pk.u);
          }
        }
      }
      __syncthreads();   // per-wave s_waitcnt vmcnt(0) before barrier => stores drained
      if (tid == 0) sysstore_u8(readyb + c * 8 + s, (unsigned char)1);
    }
  }
}

// out1 = h @ Wp^T + bp   (128x256)
extern "C" __global__ void proj_hp(const float* __restrict__ h,
                                   const float* __restrict__ Wp,
                                   const float* __restrict__ bp,
                                   float* __restrict__ hp)
{
  const int bb = blockIdx.x;
  const int j  = threadIdx.x;  // 256
  const float4* hv = (const float4*)(h + bb * HH);
  const float4* wr = (const float4*)(Wp + j * HH);
  float s = 0.f;
  for (int k = 0; k < HH / 4; k++) {
    const float4 a = hv[k], w = wr[k];
    s += a.x * w.x + a.y * w.y + a.z * w.z + a.w * w.w;
  }
  hp[bb * HH + j] = s + bp[j];
}

// out = hp @ Wo^T + bo   (128x128)
extern "C" __global__ void proj_out(const float* __restrict__ hp,
                                    const float* __restrict__ Wo,
                                    const float* __restrict__ bo,
                                    float* __restrict__ out)
{
  const int bb = blockIdx.x;
  const int o  = threadIdx.x;  // 128
  const float4* hv = (const float4*)(hp + bb * HH);
  const float4* wr = (const float4*)(Wo + o * HH);
  float s = 0.f;
  for (int k = 0; k < HH / 4; k++) {
    const float4 a = hv[k], w = wr[k];
    s += a.x * w.x + a.y * w.y + a.z * w.z + a.w * w.w;
  }
  out[bb * OO + o] = s + bo[o];
}

extern "C" void kernel_launch(void* const* d_in, const int* in_sizes, int n_in,
                              void* d_out, int out_size, void* d_ws, size_t ws_size,
                              hipStream_t stream)
{
  const float* x    = (const float*)d_in[0];
  const int*   ln   = (const int*)  d_in[1];
  const float* W    = (const float*)d_in[2];
  const float* R    = (const float*)d_in[3];
  const float* bvec = (const float*)d_in[4];
  const float* btk  = (const float*)d_in[5];
  const float* Wp   = (const float*)d_in[6];
  const float* bp   = (const float*)d_in[7];
  const float* Wo   = (const float*)d_in[8];
  const float* bo   = (const float*)d_in[9];
  float* out = (float*)d_out;

  // Workspace layout. No init pass needed:
  //   prog[] poisoned 0xAA..: negative => producers wait until consumers publish.
  //   readyb[] poisoned 0xAA != 1 => consumers wait until producers publish.
  char* ws = (char*)d_ws;
  int*                prog    = (int*)ws;                       // 32 B
  unsigned char*      readyb  = (unsigned char*)(ws + 64);      // MAXCH*8 = 4112 B
  float*              h_final = (float*)(ws + 8192);            // 128 KB
  float*              hp      = (float*)(ws + 8192 + 131072);   // 128 KB
  unsigned long long* ring    = (unsigned long long*)(ws + (1 << 20));  // 25.2 MB

  hipLaunchKernelGGL(lstm_all, dim3(NCG + NPS * NPL), dim3(512), 0, stream,
                     x, ln, W, R, bvec, btk, ring, readyb, prog, h_final);
  hipLaunchKernelGGL(proj_hp,  dim3(BB), dim3(HH), 0, stream, h_final, Wp, bp, hp);
  hipLaunchKernelGGL(proj_out, dim3(BB), dim3(OO), 0, stream, hp, Wo, bo, out);
}

// Round 6
// 5989.751 us; speedup vs baseline: 1.1964x; 1.0420x over previous
//
#include <hip/hip_runtime.h>

// Problem constants
#define BB    128   // batch
#define LL    2048  // seq len
#define FF    128   // input features
#define HH    256   // hidden
#define OO    128   // output
#define NTICK 5
#define GC    16    // chains per consumer group
#define NCG   8     // consumer groups (blocks 0..7)
#define CH    4     // timesteps per ring chunk
#define DRING 128   // ring depth (timesteps); 25 MB f16
#define NPS   8     // producer col-slices (96 cols each)
#define NPL   16    // producer chunk-lanes
#define MAXT  (LL + NTICK)
#define MAXCH ((MAXT + CH - 1) / CH)
#define RDY8  0x0101010101010101ULL

// Gate-column pre-scales folded into W/R/b/tick so the gate body uses bare
// v_exp_f32 (exp2) with no constant multiplies:
//   ci cols  (0..255):   * 2*log2(e)  -> ea = exp2(pc_s) = e^{2 pc}
//   ig cols (256..511):  * -log2(e)   -> eb = exp2(pi_s) = e^{-pi}
//   og cols (512..767):  * -log2(e)   -> ed = exp2(po_s) = e^{-po}
// Cell state c is kept in ci-scaled units (c' = 2log2e * c).
#define SC_CI  (2.8853900817779268f)
#define SC_GT  (-1.4426950408889634f)

typedef __attribute__((ext_vector_type(8))) _Float16 half8;
typedef __attribute__((ext_vector_type(2))) __fp16 fp16x2;
typedef __attribute__((ext_vector_type(4))) float f32x4;

union U64H8 { unsigned long long u[2]; _Float16 h[8]; fp16x2 p[4]; };
union U64H4 { unsigned long long u; _Float16 h[4]; };

__device__ __forceinline__ float fast_rcp(float x) { return __builtin_amdgcn_rcpf(x); }
__device__ __forceinline__ float fast_exp2(float x) { return __builtin_amdgcn_exp2f(x); }

// Relaxed system-scope ops (sc0 sc1): bypass L1/L2, coherent at MALL.
// RELAXED => no buffer_inv/buffer_wbl2 cache maintenance emitted.
__device__ __forceinline__ unsigned long long sysload_u64(const unsigned long long* p) {
  return __hip_atomic_load(p, __ATOMIC_RELAXED, __HIP_MEMORY_SCOPE_SYSTEM);
}
__device__ __forceinline__ void sysstore_u64(unsigned long long* p, unsigned long long v) {
  __hip_atomic_store(p, v, __ATOMIC_RELAXED, __HIP_MEMORY_SCOPE_SYSTEM);
}
__device__ __forceinline__ int sysload_i32(const int* p) {
  return __hip_atomic_load(p, __ATOMIC_RELAXED, __HIP_MEMORY_SCOPE_SYSTEM);
}
__device__ __forceinline__ void sysstore_i32(int* p, int v) {
  __hip_atomic_store(p, v, __ATOMIC_RELAXED, __HIP_MEMORY_SCOPE_SYSTEM);
}
__device__ __forceinline__ void sysstore_u8(unsigned char* p, unsigned char v) {
  __hip_atomic_store(p, v, __ATOMIC_RELAXED, __HIP_MEMORY_SCOPE_SYSTEM);
}

// Raw barrier with LDS-only drain: ring prefetch loads (vmcnt) stay in flight
// across the barrier; per-wave register-dependency tracking still inserts the
// vmcnt wait before the first USE of the loaded registers next iteration.
// All cross-thread state in the consumer loop is LDS (pre_s/h_s) => lgkmcnt
// is the only drain correctness needs. (The deferred prog store is a
// monotonic watermark; producers tolerate staleness.)
__device__ __forceinline__ void sync_lds_only() {
  asm volatile("s_waitcnt lgkmcnt(0)" ::: "memory");
  __builtin_amdgcn_s_barrier();
  asm volatile("" ::: "memory");
}

// Blocks 0..7: consumers (one chain-group of 16 chains per block, 8 waves;
//   R register-stationary, per-step sync = LDS barriers only).
// Blocks 8..135: producers (col-slice s = pid&7, chunk-lane = pid>>3;
//   compute pre_x = bias + tick*[len<=t<len+5] + [t<len]*x_t@W into ring).
//
// MFMA layout note: fragments are loaded as B[k][n] (n=lane&15, k=quad*8+j).
// Passing the WEIGHT fragment in the A slot makes HW read it as A[m=col][k],
// and the activation fragment in the B slot as B[k][n=chain]. Then
// D = W^T·act^T and C-layout reg r of lane nl = pre[chain=nl][col=..+quad*4+r],
// which is what the spill / ring-write code assumes.
extern "C" __global__ __launch_bounds__(512, 1)
void lstm_all(const float* __restrict__ x, const int* __restrict__ lens,
              const float* __restrict__ W, const float* __restrict__ R,
              const float* __restrict__ bvec, const float* __restrict__ btk,
              unsigned long long* ring, unsigned char* readyb,
              int* prog, float* __restrict__ h_final)
{
  const int tid  = threadIdx.x;
  const int lane = tid & 63;
  const int wv   = tid >> 6;
  const int quad = lane >> 4;
  const int nl   = lane & 15;
  const int bx   = blockIdx.x;

  __shared__ int lens_s[BB];
  if (tid < BB) lens_s[tid] = lens[tid];
  __syncthreads();

  if (bx < NCG) {
    // ======================= CONSUMER =======================
    const int cg = bx, cbase = cg * GC;
    __shared__ float    pre_s[GC][772];   // h@R pre-activations, fp32 (scaled units)
    __shared__ _Float16 h_s[GC][264];     // hidden state (f16, true units)

    for (int i = tid; i < GC * 772; i += 512) ((float*)pre_s)[i] = 0.f;
    for (int i = tid; i < GC * 264; i += 512) ((_Float16*)h_s)[i] = (_Float16)0.f;

    int mxl = 0;
    #pragma unroll
    for (int i = 0; i < GC; i++) mxl = max(mxl, lens_s[cbase + i]);
    const int Tg = mxl + NTICK;

    // R fragments, register-stationary, column-scaled. Wave wv owns cols
    // [wv*96, wv*96+96): loaded as B[k][n]: n = lane&15, k = quad*8+j.
    half8 rfr[6][8];
    const int colw = wv * 96;
    #pragma unroll
    for (int tile = 0; tile < 6; tile++) {
      const int scol = colw + tile * 16;
      const float rsc = (scol < HH) ? SC_CI : SC_GT;
      const int col = scol + nl;
      #pragma unroll
      for (int kc = 0; kc < 8; kc++) {
        const int k0 = kc * 32 + quad * 8;
        half8 v;
        #pragma unroll
        for (int j = 0; j < 8; j++) v[j] = (_Float16)(R[(k0 + j) * (3 * HH) + col] * rsc);
        rfr[tile][kc] = v;
      }
    }

    // gate-thread identity: chain m, h-dims hj..hj+7
    const int m  = tid >> 5;
    const int hj = (tid & 31) * 8;
    const int lenm = lens_s[cbase + m];

    // cell state: thread-private -> registers (ci-scaled units)
    float cst[8];
    #pragma unroll
    for (int d = 0; d < 8; d++) cst[d] = 0.f;

    const unsigned long long* rb = (const unsigned long long*)readyb;

    // initial: wait chunk 0, prefetch xw(0)
    while (sysload_u64(rb + 0) != RDY8) {}
    asm volatile("" ::: "memory");
    unsigned long long xw[6];
    {
      const unsigned long long* rp = ring + ((((long)0 * BB + cbase + m) * 768 + hj) >> 2);
      xw[0] = sysload_u64(rp);       xw[1] = sysload_u64(rp + 1);
      xw[2] = sysload_u64(rp + 64);  xw[3] = sysload_u64(rp + 65);
      xw[4] = sysload_u64(rp + 128); xw[5] = sysload_u64(rp + 129);
    }
    unsigned long long rvn = sysload_u64(rb + 1);
    int cur_chunk = 0;
    __syncthreads();

    for (int t = 0; t < Tg; ++t) {
      // ---- recurrent MFMA phase: pre_h = h(t-1) @ R
      if (t > 0) {
        f32x4 acc[6];
        #pragma unroll
        for (int i = 0; i < 6; i++) acc[i] = (f32x4){0.f, 0.f, 0.f, 0.f};
        const _Float16* hrow = &h_s[nl][0];
        #pragma unroll
        for (int kc = 0; kc < 8; kc++) {
          const half8 a = *(const half8*)(hrow + kc * 32 + quad * 8);
          #pragma unroll
          for (int tile = 0; tile < 6; tile++)
            acc[tile] = __builtin_amdgcn_mfma_f32_16x16x32_f16(rfr[tile][kc], a, acc[tile], 0, 0, 0);
        }
        // spill: D = R^T h^T => lane nl reg r = pre[chain=nl][colw+tile*16+quad*4+r]
        #pragma unroll
        for (int tile = 0; tile < 6; tile++)
          *(f32x4*)(&pre_s[nl][colw + tile * 16 + quad * 4]) = acc[tile];
      }
      sync_lds_only();   // pre_s(t) visible; prior ring loads NOT drained here

      // ---- capture xw(t) into gate registers, then issue prefetch xw(t+1)
      // EARLY so its ~900cy system-scope latency hides under the gate phase
      // and the next MFMA phase (no vmcnt drain at either barrier).
      U64H8 uc, ui, uo;
      uc.u[0] = xw[0]; uc.u[1] = xw[1];
      ui.u[0] = xw[2]; ui.u[1] = xw[3];
      uo.u[0] = xw[4]; uo.u[1] = xw[5];

      if (t + 1 < Tg && t + 1 < lenm + NTICK) {
        const int nc = (t + 1) >> 2;
        if (nc != cur_chunk) {
          while (rvn != RDY8) rvn = sysload_u64(rb + nc);
          cur_chunk = nc;
          rvn = (nc + 1 < MAXCH) ? sysload_u64(rb + nc + 1) : RDY8;
        }
        asm volatile("" ::: "memory");
        const int slot = (t + 1) & (DRING - 1);
        const unsigned long long* rp = ring + ((((long)slot * BB + cbase + m) * 768 + hj) >> 2);
        xw[0] = sysload_u64(rp);       xw[1] = sysload_u64(rp + 1);
        xw[2] = sysload_u64(rp + 64);  xw[3] = sysload_u64(rp + 65);
        xw[4] = sysload_u64(rp + 128); xw[5] = sysload_u64(rp + 129);
      }

      // ---- gate phase (per-thread; execz-skipped when whole wave frozen)
      if (t < lenm + NTICK) {
        const float* pr = &pre_s[m][0];
        float pci[8], pig[8], pog[8], hh[8];
        *(float4*)(pci)     = *(const float4*)(pr + hj);
        *(float4*)(pci + 4) = *(const float4*)(pr + hj + 4);
        *(float4*)(pig)     = *(const float4*)(pr + 256 + hj);
        *(float4*)(pig + 4) = *(const float4*)(pr + 256 + hj + 4);
        *(float4*)(pog)     = *(const float4*)(pr + 512 + hj);
        *(float4*)(pog + 4) = *(const float4*)(pr + 512 + hj + 4);
        #pragma unroll
        for (int d = 0; d < 8; d++) {
          // scaled units: pc = 2log2e*pc_true, pi = -log2e*pi_true, po = -log2e*po_true
          const float pc = pci[d] + (float)uc.h[d];
          const float pi = pig[d] + (float)ui.h[d];
          const float po = pog[d] + (float)uo.h[d];
          // dc = tanh(pc)*sigmoid(pi) = (e^{2pc}-1) / ((e^{2pc}+1)(1+e^{-pi}))
          const float ea = fast_exp2(__builtin_fminf(pc, 43.0f));   // e^{2 pc_true}
          const float eb = fast_exp2(pi);                           // e^{-pi_true}
          const float t1 = __builtin_fmaf(ea, SC_CI, -SC_CI);       // 2log2e*(ea-1)
          const float cn = __builtin_fmaf(t1, fast_rcp((ea + 1.f) * (1.f + eb)), cst[d]);
          const float ec = fast_exp2(__builtin_fminf(cn, 43.0f));   // e^{2 c_true}
          const float ed = fast_exp2(po);                           // e^{-po_true}
          hh[d] = (ec - 1.f) * fast_rcp((ec + 1.f) * (1.f + ed));
          cst[d] = cn;
        }
        U64H8 up;
        up.p[0] = __builtin_amdgcn_cvt_pkrtz(hh[0], hh[1]);
        up.p[1] = __builtin_amdgcn_cvt_pkrtz(hh[2], hh[3]);
        up.p[2] = __builtin_amdgcn_cvt_pkrtz(hh[4], hh[5]);
        up.p[3] = __builtin_amdgcn_cvt_pkrtz(hh[6], hh[7]);
        *(half8*)(&h_s[m][hj]) = *(half8*)up.h;
        if (t == lenm + NTICK - 1) {
          float* hf = h_final + (cbase + m) * HH + hj;
          *(float4*)(hf)     = *(float4*)(hh);
          *(float4*)(hf + 4) = *(float4*)(hh + 4);
        }
      }

      sync_lds_only();   // h_s(t) visible; ring prefetch stays in flight
      if (tid == 0) sysstore_i32(prog + cg, t);
    }
    if (tid == 0) sysstore_i32(prog + cg, 1 << 20);

  } else {
    // ======================= PRODUCER =======================
    const int pid = bx - NCG;       // 0..127
    const int s   = pid & 7;        // col slice (96 cols)
    const int pl  = pid >> 3;       // chunk lane 0..15

    int mxall = 0;
    #pragma unroll 8
    for (int i = 0; i < BB; i++) mxall = max(mxall, lens_s[i]);
    const int Tall = mxall + NTICK;
    const int nch  = (Tall + CH - 1) / CH;

    half8 wfr[4];
    float bias4[4], tick4[4];
    int col0w = 0;
    if (wv < 6) {
      col0w = s * 96 + wv * 16;
      const float wsc = (col0w < HH) ? SC_CI : SC_GT;   // whole 16-col tile same gate
      #pragma unroll
      for (int kc = 0; kc < 4; kc++) {
        const int k0 = kc * 32 + quad * 8;
        half8 v;
        #pragma unroll
        for (int j = 0; j < 8; j++) v[j] = (_Float16)(W[(k0 + j) * (3 * HH) + col0w + nl] * wsc);
        wfr[kc] = v;
      }
      float4 b4 = *(const float4*)(bvec + col0w + quad * 4);
      float4 t4 = *(const float4*)(btk  + col0w + quad * 4);
      bias4[0] = b4.x * wsc; bias4[1] = b4.y * wsc; bias4[2] = b4.z * wsc; bias4[3] = b4.w * wsc;
      tick4[0] = t4.x * wsc; tick4[1] = t4.y * wsc; tick4[2] = t4.z * wsc; tick4[3] = t4.w * wsc;
    }

    for (int c = pl; c < nch; c += NPL) {
      if (c * CH >= DRING) {           // flow control: don't overwrite unread slots
        if (tid == 0) {
          const int need = c * CH + CH - DRING;
          for (;;) {
            int mn = 0x7fffffff;
            #pragma unroll
            for (int g = 0; g < NCG; g++) mn = min(mn, sysload_i32(prog + g));
            if (mn >= need) break;
          }
        }
        __syncthreads();
      }
      if (wv < 6) {
        for (int tt = 0; tt < CH; tt++) {
          const int t = c * CH + tt;
          const int slot = t & (DRING - 1);
          #pragma unroll 2
          for (int bt = 0; bt < 8; bt++) {
            const int b = bt * 16 + nl;
            const int lenb = lens_s[b];
            f32x4 acc = {0.f, 0.f, 0.f, 0.f};
            if (t < LL) {
              const float* xp = x + ((long)b * LL + t) * FF + quad * 8;
              #pragma unroll
              for (int kc = 0; kc < 4; kc++) {
                const float4 u0 = *(const float4*)(xp + kc * 32);
                const float4 u1 = *(const float4*)(xp + kc * 32 + 4);
                half8 a;
                a[0] = (_Float16)u0.x; a[1] = (_Float16)u0.y;
                a[2] = (_Float16)u0.z; a[3] = (_Float16)u0.w;
                a[4] = (_Float16)u1.x; a[5] = (_Float16)u1.y;
                a[6] = (_Float16)u1.z; a[7] = (_Float16)u1.w;
                // W-frag in A slot, x-frag in B slot: D = W^T x^T =>
                // lane nl reg r = pre_x[batch=bt*16+nl][col0w+quad*4+r]
                acc = __builtin_amdgcn_mfma_f32_16x16x32_f16(wfr[kc], a, acc, 0, 0, 0);
              }
            }
            U64H4 pk;
            const bool in_x  = (t < lenb);
            const bool in_tk = (t >= lenb) && (t < lenb + NTICK);
            #pragma unroll
            for (int r = 0; r < 4; r++) {
              float v = bias4[r];
              if (in_x)  v += acc[r];
              if (in_tk) v += tick4[r];
              pk.h[r] = (_Float16)v;
            }
            sysstore_u64(ring + ((((long)slot * BB + b) * 768 + col0w + quad * 4) >> 2), pk.u);
          }
        }
      }
      __syncthreads();   // per-wave s_waitcnt vmcnt(0) before barrier => stores drained
      if (tid == 0) sysstore_u8(readyb + c * 8 + s, (unsigned char)1);
    }
  }
}

// out1 = h @ Wp^T + bp   (128x256)
extern "C" __global__ void proj_hp(const float* __restrict__ h,
                                   const float* __restrict__ Wp,
                                   const float* __restrict__ bp,
                                   float* __restrict__ hp)
{
  const int bb = blockIdx.x;
  const int j  = threadIdx.x;  // 256
  const float4* hv = (const float4*)(h + bb * HH);
  const float4* wr = (const float4*)(Wp + j * HH);
  float s = 0.f;
  for (int k = 0; k < HH / 4; k++) {
    const float4 a = hv[k], w = wr[k];
    s += a.x * w.x + a.y * w.y + a.z * w.z + a.w * w.w;
  }
  hp[bb * HH + j] = s + bp[j];
}

// out = hp @ Wo^T + bo   (128x128)
extern "C" __global__ void proj_out(const float* __restrict__ hp,
                                    const float* __restrict__ Wo,
                                    const float* __restrict__ bo,
                                    float* __restrict__ out)
{
  const int bb = blockIdx.x;
  const int o  = threadIdx.x;  // 128
  const float4* hv = (const float4*)(hp + bb * HH);
  const float4* wr = (const float4*)(Wo + o * HH);
  float s = 0.f;
  for (int k = 0; k < HH / 4; k++) {
    const float4 a = hv[k], w = wr[k];
    s += a.x * w.x + a.y * w.y + a.z * w.z + a.w * w.w;
  }
  out[bb * OO + o] = s + bo[o];
}

extern "C" void kernel_launch(void* const* d_in, const int* in_sizes, int n_in,
                              void* d_out, int out_size, void* d_ws, size_t ws_size,
                              hipStream_t stream)
{
  const float* x    = (const float*)d_in[0];
  const int*   ln   = (const int*)  d_in[1];
  const float* W    = (const float*)d_in[2];
  const float* R    = (const float*)d_in[3];
  const float* bvec = (const float*)d_in[4];
  const float* btk  = (const float*)d_in[5];
  const float* Wp   = (const float*)d_in[6];
  const float* bp   = (const float*)d_in[7];
  const float* Wo   = (const float*)d_in[8];
  const float* bo   = (const float*)d_in[9];
  float* out = (float*)d_out;

  // Workspace layout. No init pass needed:
  //   prog[] poisoned 0xAA..: negative => producers wait until consumers publish.
  //   readyb[] poisoned 0xAA != 1 => consumers wait until producers publish.
  char* ws = (char*)d_ws;
  int*                prog    = (int*)ws;                       // 32 B
  unsigned char*      readyb  = (unsigned char*)(ws + 64);      // MAXCH*8 = 4112 B
  float*              h_final = (float*)(ws + 8192);            // 128 KB
  float*              hp      = (float*)(ws + 8192 + 131072);   // 128 KB
  unsigned long long* ring    = (unsigned long long*)(ws + (1 << 20));  // 25.2 MB

  hipLaunchKernelGGL(lstm_all, dim3(NCG + NPS * NPL), dim3(512), 0, stream,
                     x, ln, W, R, bvec, btk, ring, readyb, prog, h_final);
  hipLaunchKernelGGL(proj_hp,  dim3(BB), dim3(HH), 0, stream, h_final, Wp, bp, hp);
  hipLaunchKernelGGL(proj_out, dim3(BB), dim3(OO), 0, stream, hp, Wo, bo, out);
}

// Round 7
// 5851.721 us; speedup vs baseline: 1.2246x; 1.0236x over previous
//
#include <hip/hip_runtime.h>

// Problem constants
#define BB    128   // batch
#define LL    2048  // seq len
#define FF    128   // input features
#define HH    256   // hidden
#define OO    128   // output
#define NTICK 5
#define GC    16    // chains per consumer group
#define NCG   8     // consumer groups (blocks 0..7)
#define CH    4     // timesteps per ring chunk
#define DRING 128   // ring depth (timesteps); 25 MB f16
#define NPS   8     // producer col-slices (96 cols each)
#define NPL   16    // producer chunk-lanes
#define MAXT  (LL + NTICK)
#define MAXCH ((MAXT + CH - 1) / CH)
#define RDY8  0x0101010101010101ULL

// Gate-column pre-scales folded into W/R/b/tick so the gate body uses bare
// v_exp_f32 (exp2) with no constant multiplies:
//   ci cols  (0..255):   * 2*log2(e)  -> ea = exp2(pc_s) = e^{2 pc}
//   ig cols (256..511):  * -log2(e)   -> eb = exp2(pi_s) = e^{-pi}
//   og cols (512..767):  * -log2(e)   -> ed = exp2(po_s) = e^{-po}
// Cell state c is kept in ci-scaled units (c' = 2log2e * c).
#define SC_CI  (2.8853900817779268f)
#define SC_GT  (-1.4426950408889634f)

typedef __attribute__((ext_vector_type(8))) _Float16 half8;
typedef __attribute__((ext_vector_type(2))) __fp16 fp16x2;
typedef __attribute__((ext_vector_type(4))) float f32x4;

union U64H4 { unsigned long long u; _Float16 h[4]; fp16x2 p[2]; };

__device__ __forceinline__ float fast_rcp(float x) { return __builtin_amdgcn_rcpf(x); }
__device__ __forceinline__ float fast_exp2(float x) { return __builtin_amdgcn_exp2f(x); }

// Relaxed system-scope ops (sc0 sc1): bypass L1/L2, coherent at MALL.
__device__ __forceinline__ unsigned long long sysload_u64(const unsigned long long* p) {
  return __hip_atomic_load(p, __ATOMIC_RELAXED, __HIP_MEMORY_SCOPE_SYSTEM);
}
__device__ __forceinline__ void sysstore_u64(unsigned long long* p, unsigned long long v) {
  __hip_atomic_store(p, v, __ATOMIC_RELAXED, __HIP_MEMORY_SCOPE_SYSTEM);
}
__device__ __forceinline__ int sysload_i32(const int* p) {
  return __hip_atomic_load(p, __ATOMIC_RELAXED, __HIP_MEMORY_SCOPE_SYSTEM);
}
__device__ __forceinline__ void sysstore_i32(int* p, int v) {
  __hip_atomic_store(p, v, __ATOMIC_RELAXED, __HIP_MEMORY_SCOPE_SYSTEM);
}
__device__ __forceinline__ void sysstore_u8(unsigned char* p, unsigned char v) {
  __hip_atomic_store(p, v, __ATOMIC_RELAXED, __HIP_MEMORY_SCOPE_SYSTEM);
}

// Raw barrier with LDS-only drain: ring prefetch loads (vmcnt) stay in flight
// across the barrier; per-wave register-dependency tracking inserts the vmcnt
// wait before the first USE of the loaded registers next iteration. All
// cross-thread state in the consumer loop is LDS (pre_s/h_s) => lgkmcnt is
// the only drain correctness needs.
__device__ __forceinline__ void sync_lds_only() {
  asm volatile("s_waitcnt lgkmcnt(0)" ::: "memory");
  __builtin_amdgcn_s_barrier();
  asm volatile("" ::: "memory");
}

// Blocks 0..7: consumers (16 chains per block, 8 waves; R register-stationary).
// Blocks 8..135: producers (col-slice s = pid&7, chunk-lane = pid>>3).
//
// MFMA layout note: fragments are loaded as B[k][n] (n=lane&15, k=quad*8+j).
// Weight fragment in the A slot => D = W^T.act^T; C-layout reg r of lane nl =
// pre[chain=nl][col = base + quad*4 + r].
//
// Gate-thread dim mapping (bank-group balance): thread (m = tid>>5,
// q32 = tid&31) owns dims {4*q32 + 128k : k=0,1}, 4 dims per chunk.
// pre_s reads are then f32x4 at dword 4*q32 (+128k +256g) -> bank-group
// (q32 mod 8): all 8 groups hit evenly (vs the old 8-contig-dims mapping
// which used only 4 of 8 groups = 2x LDS serialization on every gate read).
// Ring loads stay 6 u64/thread (one u64 = 4 cols = one chunk per gate).
extern "C" __global__ __launch_bounds__(512, 1)
void lstm_all(const float* __restrict__ x, const int* __restrict__ lens,
              const float* __restrict__ W, const float* __restrict__ R,
              const float* __restrict__ bvec, const float* __restrict__ btk,
              unsigned long long* ring, unsigned char* readyb,
              int* prog, float* __restrict__ h_final)
{
  const int tid  = threadIdx.x;
  const int lane = tid & 63;
  const int wv   = tid >> 6;
  const int quad = lane >> 4;
  const int nl   = lane & 15;
  const int bx   = blockIdx.x;

  __shared__ int lens_s[BB];
  if (tid < BB) lens_s[tid] = lens[tid];
  __syncthreads();

  if (bx < NCG) {
    // ======================= CONSUMER =======================
    const int cg = bx, cbase = cg * GC;
    __shared__ float    pre_s[GC][772];   // h@R pre-activations, fp32 (scaled units)
    __shared__ _Float16 h_s[GC][264];     // hidden state (f16, true units)

    for (int i = tid; i < GC * 772; i += 512) ((float*)pre_s)[i] = 0.f;
    for (int i = tid; i < GC * 264; i += 512) ((_Float16*)h_s)[i] = (_Float16)0.f;

    int mxl = 0;
    #pragma unroll
    for (int i = 0; i < GC; i++) mxl = max(mxl, lens_s[cbase + i]);
    const int Tg = mxl + NTICK;

    // R fragments, register-stationary, column-scaled. Wave wv owns cols
    // [wv*96, wv*96+96): loaded as B[k][n]: n = lane&15, k = quad*8+j.
    half8 rfr[6][8];
    const int colw = wv * 96;
    #pragma unroll
    for (int tile = 0; tile < 6; tile++) {
      const int scol = colw + tile * 16;
      const float rsc = (scol < HH) ? SC_CI : SC_GT;
      const int col = scol + nl;
      #pragma unroll
      for (int kc = 0; kc < 8; kc++) {
        const int k0 = kc * 32 + quad * 8;
        half8 v;
        #pragma unroll
        for (int j = 0; j < 8; j++) v[j] = (_Float16)(R[(k0 + j) * (3 * HH) + col] * rsc);
        rfr[tile][kc] = v;
      }
    }

    // gate-thread identity: chain m, dim chunks {4*q32 + 128k}
    const int m   = tid >> 5;
    const int q32 = tid & 31;
    const int d0  = q32 * 4;
    const int lenm = lens_s[cbase + m];

    // cell state: thread-private registers (ci-scaled units); [k*4 + r]
    float cst[8];
    #pragma unroll
    for (int d = 0; d < 8; d++) cst[d] = 0.f;

    const unsigned long long* rb = (const unsigned long long*)readyb;

    // initial: wait chunk 0, prefetch xw(0).
    // xw[g*2+k] = ring u64 at chain-row + 64g + 32k + q32  (col = 256g+128k+d0)
    while (sysload_u64(rb + 0) != RDY8) {}
    asm volatile("" ::: "memory");
    unsigned long long xw[6];
    {
      const unsigned long long* rp = ring + (((long)0 * BB + cbase + m) * 192) + q32;
      xw[0] = sysload_u64(rp);       xw[1] = sysload_u64(rp + 32);
      xw[2] = sysload_u64(rp + 64);  xw[3] = sysload_u64(rp + 96);
      xw[4] = sysload_u64(rp + 128); xw[5] = sysload_u64(rp + 160);
    }
    unsigned long long rvn = sysload_u64(rb + 1);
    int cur_chunk = 0;
    __syncthreads();

    for (int t = 0; t < Tg; ++t) {
      // ---- recurrent MFMA phase: pre_h = h(t-1) @ R
      if (t > 0) {
        f32x4 acc[6];
        #pragma unroll
        for (int i = 0; i < 6; i++) acc[i] = (f32x4){0.f, 0.f, 0.f, 0.f};
        const _Float16* hrow = &h_s[nl][0];
        #pragma unroll
        for (int kc = 0; kc < 8; kc++) {
          const half8 a = *(const half8*)(hrow + kc * 32 + quad * 8);
          #pragma unroll
          for (int tile = 0; tile < 6; tile++)
            acc[tile] = __builtin_amdgcn_mfma_f32_16x16x32_f16(rfr[tile][kc], a, acc[tile], 0, 0, 0);
        }
        // spill: lane nl reg r = pre[chain=nl][colw+tile*16+quad*4+r]
        #pragma unroll
        for (int tile = 0; tile < 6; tile++)
          *(f32x4*)(&pre_s[nl][colw + tile * 16 + quad * 4]) = acc[tile];
      }
      sync_lds_only();   // pre_s(t) visible; prior ring loads NOT drained here

      // ---- capture xw(t), then issue prefetch xw(t+1) EARLY so its latency
      // hides under the gate phase + next MFMA phase (no vmcnt drain at barriers)
      unsigned long long xwc[6];
      #pragma unroll
      for (int i = 0; i < 6; i++) xwc[i] = xw[i];

      if (t + 1 < Tg && t + 1 < lenm + NTICK) {
        const int nc = (t + 1) >> 2;
        if (nc != cur_chunk) {
          while (rvn != RDY8) rvn = sysload_u64(rb + nc);
          cur_chunk = nc;
          rvn = (nc + 1 < MAXCH) ? sysload_u64(rb + nc + 1) : RDY8;
        }
        asm volatile("" ::: "memory");
        const int slot = (t + 1) & (DRING - 1);
        const unsigned long long* rp = ring + (((long)slot * BB + cbase + m) * 192) + q32;
        xw[0] = sysload_u64(rp);       xw[1] = sysload_u64(rp + 32);
        xw[2] = sysload_u64(rp + 64);  xw[3] = sysload_u64(rp + 96);
        xw[4] = sysload_u64(rp + 128); xw[5] = sysload_u64(rp + 160);
      }

      // ---- gate phase (per-thread; execz-skipped when whole wave frozen)
      if (t < lenm + NTICK) {
        const float* pr = &pre_s[m][0];
        #pragma unroll
        for (int k = 0; k < 2; k++) {
          const int dk = d0 + 128 * k;
          U64H4 uck, uik, uok;
          uck.u = xwc[k];     // ci cols
          uik.u = xwc[2 + k]; // ig cols
          uok.u = xwc[4 + k]; // og cols
          const f32x4 pci4 = *(const f32x4*)(pr + dk);
          const f32x4 pig4 = *(const f32x4*)(pr + 256 + dk);
          const f32x4 pog4 = *(const f32x4*)(pr + 512 + dk);
          float hh[4];
          #pragma unroll
          for (int r = 0; r < 4; r++) {
            // scaled units: pc = 2log2e*pc_true, pi = -log2e*pi_true, po = -log2e*po_true
            const float pc = pci4[r] + (float)uck.h[r];
            const float pi = pig4[r] + (float)uik.h[r];
            const float po = pog4[r] + (float)uok.h[r];
            // dc = tanh(pc)*sigmoid(pi) = (e^{2pc}-1) / ((e^{2pc}+1)(1+e^{-pi}))
            const float ea = fast_exp2(__builtin_fminf(pc, 43.0f));   // e^{2 pc_true}
            const float eb = fast_exp2(pi);                           // e^{-pi_true}
            const float t1 = __builtin_fmaf(ea, SC_CI, -SC_CI);       // 2log2e*(ea-1)
            const float cn = __builtin_fmaf(t1, fast_rcp((ea + 1.f) * (1.f + eb)), cst[k * 4 + r]);
            const float ec = fast_exp2(__builtin_fminf(cn, 43.0f));   // e^{2 c_true}
            const float ed = fast_exp2(po);                           // e^{-po_true}
            hh[r] = (ec - 1.f) * fast_rcp((ec + 1.f) * (1.f + ed));
            cst[k * 4 + r] = cn;
          }
          U64H4 up;
          up.p[0] = __builtin_amdgcn_cvt_pkrtz(hh[0], hh[1]);
          up.p[1] = __builtin_amdgcn_cvt_pkrtz(hh[2], hh[3]);
          *(unsigned long long*)(&h_s[m][dk]) = up.u;
          if (t == lenm + NTICK - 1) {
            float4 v; v.x = hh[0]; v.y = hh[1]; v.z = hh[2]; v.w = hh[3];
            *(float4*)(h_final + (cbase + m) * HH + dk) = v;
          }
        }
      }

      sync_lds_only();   // h_s(t) visible; ring prefetch stays in flight
      if (tid == 0) sysstore_i32(prog + cg, t);
    }
    if (tid == 0) sysstore_i32(prog + cg, 1 << 20);

  } else {
    // ======================= PRODUCER =======================
    const int pid = bx - NCG;       // 0..127
    const int s   = pid & 7;        // col slice (96 cols)
    const int pl  = pid >> 3;       // chunk lane 0..15

    int mxall = 0;
    #pragma unroll 8
    for (int i = 0; i < BB; i++) mxall = max(mxall, lens_s[i]);
    const int Tall = mxall + NTICK;
    const int nch  = (Tall + CH - 1) / CH;

    half8 wfr[4];
    float bias4[4], tick4[4];
    int col0w = 0;
    if (wv < 6) {
      col0w = s * 96 + wv * 16;
      const float wsc = (col0w < HH) ? SC_CI : SC_GT;   // whole 16-col tile same gate
      #pragma unroll
      for (int kc = 0; kc < 4; kc++) {
        const int k0 = kc * 32 + quad * 8;
        half8 v;
        #pragma unroll
        for (int j = 0; j < 8; j++) v[j] = (_Float16)(W[(k0 + j) * (3 * HH) + col0w + nl] * wsc);
        wfr[kc] = v;
      }
      float4 b4 = *(const float4*)(bvec + col0w + quad * 4);
      float4 t4 = *(const float4*)(btk  + col0w + quad * 4);
      bias4[0] = b4.x * wsc; bias4[1] = b4.y * wsc; bias4[2] = b4.z * wsc; bias4[3] = b4.w * wsc;
      tick4[0] = t4.x * wsc; tick4[1] = t4.y * wsc; tick4[2] = t4.z * wsc; tick4[3] = t4.w * wsc;
    }

    for (int c = pl; c < nch; c += NPL) {
      if (c * CH >= DRING) {           // flow control: don't overwrite unread slots
        if (tid == 0) {
          const int need = c * CH + CH - DRING;
          for (;;) {
            int mn = 0x7fffffff;
            #pragma unroll
            for (int g = 0; g < NCG; g++) mn = min(mn, sysload_i32(prog + g));
            if (mn >= need) break;
          }
        }
        __syncthreads();
      }
      if (wv < 6) {
        for (int tt = 0; tt < CH; tt++) {
          const int t = c * CH + tt;
          const int slot = t & (DRING - 1);
          #pragma unroll 2
          for (int bt = 0; bt < 8; bt++) {
            const int b = bt * 16 + nl;
            const int lenb = lens_s[b];
            f32x4 acc = {0.f, 0.f, 0.f, 0.f};
            if (t < LL) {
              const float* xp = x + ((long)b * LL + t) * FF + quad * 8;
              #pragma unroll
              for (int kc = 0; kc < 4; kc++) {
                const float4 u0 = *(const float4*)(xp + kc * 32);
                const float4 u1 = *(const float4*)(xp + kc * 32 + 4);
                half8 a;
                a[0] = (_Float16)u0.x; a[1] = (_Float16)u0.y;
                a[2] = (_Float16)u0.z; a[3] = (_Float16)u0.w;
                a[4] = (_Float16)u1.x; a[5] = (_Float16)u1.y;
                a[6] = (_Float16)u1.z; a[7] = (_Float16)u1.w;
                // W-frag in A slot, x-frag in B slot:
                // lane nl reg r = pre_x[batch=bt*16+nl][col0w+quad*4+r]
                acc = __builtin_amdgcn_mfma_f32_16x16x32_f16(wfr[kc], a, acc, 0, 0, 0);
              }
            }
            U64H4 pk;
            const bool in_x  = (t < lenb);
            const bool in_tk = (t >= lenb) && (t < lenb + NTICK);
            #pragma unroll
            for (int r = 0; r < 4; r++) {
              float v = bias4[r];
              if (in_x)  v += acc[r];
              if (in_tk) v += tick4[r];
              pk.h[r] = (_Float16)v;
            }
            sysstore_u64(ring + ((((long)slot * BB + b) * 768 + col0w + quad * 4) >> 2), pk.u);
          }
        }
      }
      __syncthreads();   // per-wave s_waitcnt vmcnt(0) before barrier => stores drained
      if (tid == 0) sysstore_u8(readyb + c * 8 + s, (unsigned char)1);
    }
  }
}

// out1 = h @ Wp^T + bp   (128x256)
extern "C" __global__ void proj_hp(const float* __restrict__ h,
                                   const float* __restrict__ Wp,
                                   const float* __restrict__ bp,
                                   float* __restrict__ hp)
{
  const int bb = blockIdx.x;
  const int j  = threadIdx.x;  // 256
  const float4* hv = (const float4*)(h + bb * HH);
  const float4* wr = (const float4*)(Wp + j * HH);
  float s = 0.f;
  for (int k = 0; k < HH / 4; k++) {
    const float4 a = hv[k], w = wr[k];
    s += a.x * w.x + a.y * w.y + a.z * w.z + a.w * w.w;
  }
  hp[bb * HH + j] = s + bp[j];
}

// out = hp @ Wo^T + bo   (128x128)
extern "C" __global__ void proj_out(const float* __restrict__ hp,
                                    const float* __restrict__ Wo,
                                    const float* __restrict__ bo,
                                    float* __restrict__ out)
{
  const int bb = blockIdx.x;
  const int o  = threadIdx.x;  // 128
  const float4* hv = (const float4*)(hp + bb * HH);
  const float4* wr = (const float4*)(Wo + o * HH);
  float s = 0.f;
  for (int k = 0; k < HH / 4; k++) {
    const float4 a = hv[k], w = wr[k];
    s += a.x * w.x + a.y * w.y + a.z * w.z + a.w * w.w;
  }
  out[bb * OO + o] = s + bo[o];
}

extern "C" void kernel_launch(void* const* d_in, const int* in_sizes, int n_in,
                              void* d_out, int out_size, void* d_ws, size_t ws_size,
                              hipStream_t stream)
{
  const float* x    = (const float*)d_in[0];
  const int*   ln   = (const int*)  d_in[1];
  const float* W    = (const float*)d_in[2];
  const float* R    = (const float*)d_in[3];
  const float* bvec = (const float*)d_in[4];
  const float* btk  = (const float*)d_in[5];
  const float* Wp   = (const float*)d_in[6];
  const float* bp   = (const float*)d_in[7];
  const float* Wo   = (const float*)d_in[8];
  const float* bo   = (const float*)d_in[9];
  float* out = (float*)d_out;

  // Workspace layout. No init pass needed:
  //   prog[] poisoned 0xAA..: negative => producers wait until consumers publish.
  //   readyb[] poisoned 0xAA != 1 => consumers wait until producers publish.
  char* ws = (char*)d_ws;
  int*                prog    = (int*)ws;                       // 32 B
  unsigned char*      readyb  = (unsigned char*)(ws + 64);      // MAXCH*8 = 4112 B
  float*              h_final = (float*)(ws + 8192);            // 128 KB
  float*              hp      = (float*)(ws + 8192 + 131072);   // 128 KB
  unsigned long long* ring    = (unsigned long long*)(ws + (1 << 20));  // 25.2 MB

  hipLaunchKernelGGL(lstm_all, dim3(NCG + NPS * NPL), dim3(512), 0, stream,
                     x, ln, W, R, bvec, btk, ring, readyb, prog, h_final);
  hipLaunchKernelGGL(proj_hp,  dim3(BB), dim3(HH), 0, stream, h_final, Wp, bp, hp);
  hipLaunchKernelGGL(proj_out, dim3(BB), dim3(OO), 0, stream, hp, Wo, bo, out);
}